// Round 1
// baseline (233.928 us; speedup 1.0000x reference)
//
#include <hip/hip_runtime.h>

typedef __bf16 bf16x8 __attribute__((ext_vector_type(8)));
typedef float f32x4 __attribute__((ext_vector_type(4)));
typedef unsigned short u16;
typedef unsigned short u16x8 __attribute__((ext_vector_type(8)));
typedef unsigned int u32;

#define MROWS 4096      // B*T
#define DMODEL 1024
#define TSEQ 2048

// ---------- helpers ----------
__device__ __forceinline__ u32 bfr(float x) {          // fp32 -> bf16 bits, RNE
    u32 u = __float_as_uint(x);
    return (u + 0x7FFFu + ((u >> 16) & 1u)) >> 16;
}
__device__ __forceinline__ u32 pk2(float lo, float hi) { return bfr(lo) | (bfr(hi) << 16); }

__device__ __forceinline__ void gl_lds16(const void* g, void* l) {
    __builtin_amdgcn_global_load_lds(
        (const __attribute__((address_space(1))) unsigned int*)g,
        (__attribute__((address_space(3))) unsigned int*)l, 16, 0, 0);
}

// ---------- 1. convert q,k,v to bf16 ----------
__global__ __launch_bounds__(256) void cvt_x(const float* __restrict__ q,
                                             const float* __restrict__ k,
                                             const float* __restrict__ v,
                                             u16* __restrict__ X) {
    int z = blockIdx.y;
    const float* src = (z == 0) ? q : (z == 1) ? k : v;
    size_t idx = ((size_t)blockIdx.x * 256 + threadIdx.x) * 8;
    const float4* s4 = (const float4*)(src + idx);
    float4 a = s4[0], b = s4[1];
    uint4 r;
    r.x = pk2(a.x, a.y); r.y = pk2(a.z, a.w);
    r.z = pk2(b.x, b.y); r.w = pk2(b.z, b.w);
    *(uint4*)(X + (size_t)z * 4194304 + idx) = r;
}

// ---------- 2. convert + transpose weights: Wt[n][k] = W[k][n], bf16 ----------
__global__ __launch_bounds__(256) void cvt_w(const float* __restrict__ w0,
                                             const float* __restrict__ w1,
                                             const float* __restrict__ w2,
                                             const float* __restrict__ w3,
                                             u16* __restrict__ Wt) {
    int z = blockIdx.z;
    const float* W = (z == 0) ? w0 : (z == 1) ? w1 : (z == 2) ? w2 : w3;
    u16* dst = Wt + (size_t)z * 1048576;
    __shared__ float tile[32][33];
    int n0 = blockIdx.x * 32, k0 = blockIdx.y * 32;
    int tx = threadIdx.x & 31, ty = threadIdx.x >> 5;
#pragma unroll
    for (int r = 0; r < 4; r++) {
        int row = ty + r * 8;
        tile[row][tx] = W[(size_t)(k0 + row) * DMODEL + n0 + tx];
    }
    __syncthreads();
#pragma unroll
    for (int r = 0; r < 4; r++) {
        int row = ty + r * 8;
        dst[(size_t)(n0 + row) * DMODEL + k0 + tx] = (u16)bfr(tile[tx][row]);
    }
}

// ---------- 3/5. GEMM: C[M,128-tile] = A[M,1024] @ Bt[n][k]^T + bias ----------
// 128x128 tile, BK=32, 4 waves (2x2), double-buffered LDS via global_load_lds.
template <int OUT_BF16>
__global__ __launch_bounds__(256) void gemm_bt(const u16* __restrict__ Abase,
                                               const u16* __restrict__ Btbase,
                                               const float* __restrict__ b0,
                                               const float* __restrict__ b1,
                                               const float* __restrict__ b2,
                                               void* __restrict__ Cout, int ldc) {
    int z = blockIdx.z;
    const u16* A  = Abase + (size_t)z * MROWS * DMODEL;
    const u16* Bt = Btbase + (size_t)z * DMODEL * DMODEL;
    const float* bias = (z == 0) ? b0 : (z == 1) ? b1 : b2;
    int brow = blockIdx.y * 128, bcol = blockIdx.x * 128;
    int t = threadIdx.x, lane = t & 63, wid = t >> 6;
    int wr = wid >> 1, wc = wid & 1;
    int lrow = lane & 15, g = lane >> 4;

    __shared__ u16 Asm[2][128 * 32];
    __shared__ u16 Bsm[2][128 * 32];

    f32x4 zero4 = {0.f, 0.f, 0.f, 0.f};
    f32x4 acc[4][4];
#pragma unroll
    for (int i = 0; i < 4; i++)
#pragma unroll
        for (int j = 0; j < 4; j++) acc[i][j] = zero4;

    auto stage = [&](int buf, int kt) {
        int k0 = kt * 32;
#pragma unroll
        for (int i = 0; i < 2; i++) {
            int c = i * 256 + wid * 64 + lane;
            int row = c >> 2, kc = c & 3;
            gl_lds16(A + (size_t)(brow + row) * DMODEL + k0 + kc * 8,
                     &Asm[buf][(i * 256 + wid * 64) * 8]);
            gl_lds16(Bt + (size_t)(bcol + row) * DMODEL + k0 + kc * 8,
                     &Bsm[buf][(i * 256 + wid * 64) * 8]);
        }
    };

    stage(0, 0);
    __syncthreads();
    for (int kt = 0; kt < 32; ++kt) {
        int cur = kt & 1;
        if (kt < 31) stage(cur ^ 1, kt + 1);
        bf16x8 af[4], bfv[4];
#pragma unroll
        for (int mi = 0; mi < 4; mi++)
            af[mi] = *(const bf16x8*)&Asm[cur][(wr * 64 + mi * 16 + lrow) * 32 + g * 8];
#pragma unroll
        for (int nj = 0; nj < 4; nj++)
            bfv[nj] = *(const bf16x8*)&Bsm[cur][(wc * 64 + nj * 16 + lrow) * 32 + g * 8];
#pragma unroll
        for (int mi = 0; mi < 4; mi++)
#pragma unroll
            for (int nj = 0; nj < 4; nj++)
                acc[mi][nj] = __builtin_amdgcn_mfma_f32_16x16x32_bf16(af[mi], bfv[nj], acc[mi][nj], 0, 0, 0);
        __syncthreads();
    }
#pragma unroll
    for (int nj = 0; nj < 4; nj++) {
        int n = bcol + wc * 64 + nj * 16 + lrow;
        float bv = bias[n];
#pragma unroll
        for (int mi = 0; mi < 4; mi++) {
#pragma unroll
            for (int r = 0; r < 4; r++) {
                int row = brow + wr * 64 + mi * 16 + g * 4 + r;
                float val = acc[mi][nj][r] + bv;
                if (OUT_BF16)
                    ((u16*)Cout)[(size_t)row * ldc + z * DMODEL + n] = (u16)bfr(val);
                else
                    ((float*)Cout)[(size_t)row * ldc + n] = val;
            }
        }
    }
}

// ---------- 4. flash attention ----------
// block = (qtile of 64 rows, b*h). 4 waves x 16 q-rows. KV blocks of 64.
__global__ __launch_bounds__(256) void attn(const u16* __restrict__ QKV, u16* __restrict__ CTX) {
    int bh = blockIdx.y;                // b*16 + h
    int qt = blockIdx.x;                // 0..31
    int h = bh & 15;
    size_t base = (size_t)(bh >> 4) * TSEQ * 3072;
    int t = threadIdx.x, lane = t & 63, wid = t >> 6;
    int lrow = lane & 15, g = lane >> 4;

    __shared__ u16 Kl[2][4096];         // [kv][64] d-chunk-swizzled
    __shared__ u16 Vl[2][4096];         // transposed [d][kv], XOR layout
    __shared__ u16 Pl[4][1024];         // per-wave P [16 q][64 kv], slot-swizzled

    // Q fragments (hoisted, registers)
    int qrow = qt * 64 + wid * 16 + lrow;
    const u16* Qp = QKV + base + (size_t)qrow * 3072 + h * 64;
    bf16x8 aq0 = *(const bf16x8*)(Qp + g * 8);
    bf16x8 aq1 = *(const bf16x8*)(Qp + 32 + g * 8);

    f32x4 zero4 = {0.f, 0.f, 0.f, 0.f};
    f32x4 o[4];
    float m_[4], l_[4];
#pragma unroll
    for (int nj = 0; nj < 4; nj++) o[nj] = zero4;
#pragma unroll
    for (int r = 0; r < 4; r++) { m_[r] = -1e30f; l_[r] = 0.f; }

    // V staging assignment: thread -> (kv pair, 8-wide d block)
    int vkv = (t & 31) * 2;
    int vd0 = (t >> 5) * 8;
    u16x8 vr0, vr1;

    auto stageK = [&](int buf, int kvb) {
#pragma unroll
        for (int i = 0; i < 2; i++) {
            int c = i * 256 + wid * 64 + lane;
            int kv = c >> 3, kc = (c & 7) ^ (kv & 7);     // pre-swizzled source
            gl_lds16(QKV + base + (size_t)(kvb * 64 + kv) * 3072 + 1024 + h * 64 + kc * 8,
                     &Kl[buf][(i * 256 + wid * 64) * 8]);
        }
    };
    auto loadV = [&](int kvb) {
        const u16* Vp = QKV + base + (size_t)(kvb * 64) * 3072 + 2048 + h * 64;
        vr0 = *(const u16x8*)(Vp + (size_t)vkv * 3072 + vd0);
        vr1 = *(const u16x8*)(Vp + (size_t)(vkv + 1) * 3072 + vd0);
    };
    auto writeV = [&](int buf) {
#pragma unroll
        for (int e = 0; e < 8; e++) {
            int d = vd0 + e;
            int kvs = vkv ^ ((d >> 4) << 4) ^ ((d & 7) << 3);
            u32 p = (u32)vr0[e] | ((u32)vr1[e] << 16);
            *(u32*)&Vl[buf][d * 64 + kvs] = p;
        }
    };

    stageK(0, 0);
    loadV(0);
    writeV(0);
    __syncthreads();

    for (int kvb = 0; kvb < 32; ++kvb) {
        int cur = kvb & 1, nxt = cur ^ 1;
        if (kvb < 31) { stageK(nxt, kvb + 1); loadV(kvb + 1); }

        // ---- QK^T: 4 score tiles of 16x16 ----
        float s_[4][4];
#pragma unroll
        for (int tt = 0; tt < 4; tt++) {
            int kvl = tt * 16 + lrow;
            bf16x8 bk0 = *(const bf16x8*)&Kl[cur][kvl * 64 + ((g ^ (kvl & 7)) * 8)];
            bf16x8 bk1 = *(const bf16x8*)&Kl[cur][kvl * 64 + (((4 + g) ^ (kvl & 7)) * 8)];
            f32x4 s4 = zero4;
            s4 = __builtin_amdgcn_mfma_f32_16x16x32_bf16(aq0, bk0, s4, 0, 0, 0);
            s4 = __builtin_amdgcn_mfma_f32_16x16x32_bf16(aq1, bk1, s4, 0, 0, 0);
#pragma unroll
            for (int r = 0; r < 4; r++) s_[tt][r] = s4[r] * 0.125f;
        }
        // ---- online softmax (rows owned: q = g*4 + r) ----
        float pm[4], corr[4], ls[4];
#pragma unroll
        for (int r = 0; r < 4; r++)
            pm[r] = fmaxf(fmaxf(s_[0][r], s_[1][r]), fmaxf(s_[2][r], s_[3][r]));
#pragma unroll
        for (int off = 1; off < 16; off <<= 1)
#pragma unroll
            for (int r = 0; r < 4; r++) pm[r] = fmaxf(pm[r], __shfl_xor(pm[r], off));
#pragma unroll
        for (int r = 0; r < 4; r++) {
            float mn = fmaxf(m_[r], pm[r]);
            corr[r] = __expf(m_[r] - mn);
            m_[r] = mn;
            ls[r] = 0.f;
        }
#pragma unroll
        for (int tt = 0; tt < 4; tt++) {
            int kv = tt * 16 + lrow;
#pragma unroll
            for (int r = 0; r < 4; r++) {
                float p = __expf(s_[tt][r] - m_[r]);
                ls[r] += p;
                int qq = g * 4 + r;
                Pl[wid][qq * 64 + (((kv >> 3) ^ (qq & 7)) * 8) + (kv & 7)] = (u16)bfr(p);
            }
        }
#pragma unroll
        for (int off = 1; off < 16; off <<= 1)
#pragma unroll
            for (int r = 0; r < 4; r++) ls[r] += __shfl_xor(ls[r], off);
#pragma unroll
        for (int r = 0; r < 4; r++) l_[r] = l_[r] * corr[r] + ls[r];
#pragma unroll
        for (int nj = 0; nj < 4; nj++)
#pragma unroll
            for (int r = 0; r < 4; r++) o[nj][r] *= corr[r];

        if (kvb < 31) writeV(nxt);

        // ---- PV: o[16q][64d] += P @ V ----
#pragma unroll
        for (int kc = 0; kc < 2; kc++) {
            bf16x8 pa = *(const bf16x8*)&Pl[wid][lrow * 64 + (((kc * 4 + g) ^ (lrow & 7)) * 8)];
#pragma unroll
            for (int nj = 0; nj < 4; nj++) {
                int d = nj * 16 + lrow;
                bf16x8 vb = *(const bf16x8*)&Vl[cur][d * 64 + ((kc * 32 + g * 8) ^ (nj << 4) ^ ((lrow & 7) << 3))];
                o[nj] = __builtin_amdgcn_mfma_f32_16x16x32_bf16(pa, vb, o[nj], 0, 0, 0);
            }
        }
        __syncthreads();
    }

    // ---- store ctx (bf16) ----
#pragma unroll
    for (int nj = 0; nj < 4; nj++) {
#pragma unroll
        for (int r = 0; r < 4; r++) {
            int row = qt * 64 + wid * 16 + g * 4 + r;
            float val = o[nj][r] / l_[r];
            CTX[((size_t)(bh >> 4) * TSEQ + row) * DMODEL + h * 64 + nj * 16 + lrow] = (u16)bfr(val);
        }
    }
}

// ---------- launch ----------
extern "C" void kernel_launch(void* const* d_in, const int* in_sizes, int n_in,
                              void* d_out, int out_size, void* d_ws, size_t ws_size,
                              hipStream_t stream) {
    const float* q  = (const float*)d_in[0];
    const float* k  = (const float*)d_in[1];
    const float* v  = (const float*)d_in[2];
    const float* Wq = (const float*)d_in[3];
    const float* bq = (const float*)d_in[4];
    const float* Wk = (const float*)d_in[5];
    const float* bk = (const float*)d_in[6];
    const float* Wv = (const float*)d_in[7];
    const float* bv = (const float*)d_in[8];
    const float* Wo = (const float*)d_in[9];
    const float* bo = (const float*)d_in[10];

    char* ws = (char*)d_ws;
    u16* Xbf = (u16*)ws;                               // 3 * 4096*1024 bf16 = 25165824 B
    u16* Wt  = (u16*)(ws + 25165824);                  // 4 * 1024*1024 bf16 =  8388608 B
    u16* QKV = (u16*)(ws + 25165824 + 8388608);        // 4096*3072 bf16    = 25165824 B
    u16* CTX = Xbf;                                    // reuse (Xbf dead after proj GEMM)

    cvt_x<<<dim3(2048, 3), 256, 0, stream>>>(q, k, v, Xbf);
    cvt_w<<<dim3(32, 32, 4), 256, 0, stream>>>(Wq, Wk, Wv, Wo, Wt);
    gemm_bt<1><<<dim3(8, 32, 3), 256, 0, stream>>>(Xbf, Wt, bq, bk, bv, QKV, 3072);
    attn<<<dim3(32, 32), 256, 0, stream>>>(QKV, CTX);
    gemm_bt<0><<<dim3(8, 32, 1), 256, 0, stream>>>(CTX, Wt + 3 * 1048576, bo, bo, bo, d_out, 1024);
}

// Round 2
// 190.705 us; speedup vs baseline: 1.2266x; 1.2266x over previous
//
#include <hip/hip_runtime.h>

typedef __bf16 bf16x8 __attribute__((ext_vector_type(8)));
typedef float f32x4 __attribute__((ext_vector_type(4)));
typedef unsigned short u16;
typedef unsigned short u16x8 __attribute__((ext_vector_type(8)));
typedef unsigned int u32;

#define MROWS 4096      // B*T
#define DMODEL 1024
#define TSEQ 2048

// ---------- helpers ----------
__device__ __forceinline__ u32 bfr(float x) {          // fp32 -> bf16 bits, RNE
    u32 u = __float_as_uint(x);
    return (u + 0x7FFFu + ((u >> 16) & 1u)) >> 16;
}
__device__ __forceinline__ u32 pk2(float lo, float hi) { return bfr(lo) | (bfr(hi) << 16); }

__device__ __forceinline__ u32 cvtpk(float lo, float hi) {  // D.lo=bf16(lo), D.hi=bf16(hi)
    u32 r;
    asm("v_cvt_pk_bf16_f32 %0, %1, %2" : "=v"(r) : "v"(lo), "v"(hi));
    return r;
}

__device__ __forceinline__ void gl_lds16(const void* g, void* l) {
    __builtin_amdgcn_global_load_lds(
        (const __attribute__((address_space(1))) unsigned int*)g,
        (__attribute__((address_space(3))) unsigned int*)l, 16, 0, 0);
}

// ---------- 1. convert q,k,v to bf16 ----------
__global__ __launch_bounds__(256) void cvt_x(const float* __restrict__ q,
                                             const float* __restrict__ k,
                                             const float* __restrict__ v,
                                             u16* __restrict__ X) {
    int z = blockIdx.y;
    const float* src = (z == 0) ? q : (z == 1) ? k : v;
    size_t idx = ((size_t)blockIdx.x * 256 + threadIdx.x) * 8;
    const float4* s4 = (const float4*)(src + idx);
    float4 a = s4[0], b = s4[1];
    uint4 r;
    r.x = pk2(a.x, a.y); r.y = pk2(a.z, a.w);
    r.z = pk2(b.x, b.y); r.w = pk2(b.z, b.w);
    *(uint4*)(X + (size_t)z * 4194304 + idx) = r;
}

// ---------- 2. convert + transpose weights: Wt[n][k] = W[k][n], bf16 ----------
__global__ __launch_bounds__(256) void cvt_w(const float* __restrict__ w0,
                                             const float* __restrict__ w1,
                                             const float* __restrict__ w2,
                                             const float* __restrict__ w3,
                                             u16* __restrict__ Wt) {
    int z = blockIdx.z;
    const float* W = (z == 0) ? w0 : (z == 1) ? w1 : (z == 2) ? w2 : w3;
    u16* dst = Wt + (size_t)z * 1048576;
    __shared__ float tile[32][33];
    int n0 = blockIdx.x * 32, k0 = blockIdx.y * 32;
    int tx = threadIdx.x & 31, ty = threadIdx.x >> 5;
#pragma unroll
    for (int r = 0; r < 4; r++) {
        int row = ty + r * 8;
        tile[row][tx] = W[(size_t)(k0 + row) * DMODEL + n0 + tx];
    }
    __syncthreads();
#pragma unroll
    for (int r = 0; r < 4; r++) {
        int row = ty + r * 8;
        dst[(size_t)(n0 + row) * DMODEL + k0 + tx] = (u16)bfr(tile[tx][row]);
    }
}

// ---------- 3/5. GEMM: C[M,128-tile] = A[M,1024] @ Bt[n][k]^T + bias ----------
template <int OUT_BF16>
__global__ __launch_bounds__(256) void gemm_bt(const u16* __restrict__ Abase,
                                               const u16* __restrict__ Btbase,
                                               const float* __restrict__ b0,
                                               const float* __restrict__ b1,
                                               const float* __restrict__ b2,
                                               void* __restrict__ Cout, int ldc) {
    int z = blockIdx.z;
    const u16* A  = Abase + (size_t)z * MROWS * DMODEL;
    const u16* Bt = Btbase + (size_t)z * DMODEL * DMODEL;
    const float* bias = (z == 0) ? b0 : (z == 1) ? b1 : b2;
    int brow = blockIdx.y * 128, bcol = blockIdx.x * 128;
    int t = threadIdx.x, lane = t & 63, wid = t >> 6;
    int wr = wid >> 1, wc = wid & 1;
    int lrow = lane & 15, g = lane >> 4;

    __shared__ __align__(16) u16 Asm[2][128 * 32];
    __shared__ __align__(16) u16 Bsm[2][128 * 32];

    f32x4 zero4 = {0.f, 0.f, 0.f, 0.f};
    f32x4 acc[4][4];
#pragma unroll
    for (int i = 0; i < 4; i++)
#pragma unroll
        for (int j = 0; j < 4; j++) acc[i][j] = zero4;

    auto stage = [&](int buf, int kt) {
        int k0 = kt * 32;
#pragma unroll
        for (int i = 0; i < 2; i++) {
            int c = i * 256 + wid * 64 + lane;
            int row = c >> 2, kc = c & 3;
            gl_lds16(A + (size_t)(brow + row) * DMODEL + k0 + kc * 8,
                     &Asm[buf][(i * 256 + wid * 64) * 8]);
            gl_lds16(Bt + (size_t)(bcol + row) * DMODEL + k0 + kc * 8,
                     &Bsm[buf][(i * 256 + wid * 64) * 8]);
        }
    };

    stage(0, 0);
    __syncthreads();
    for (int kt = 0; kt < 32; ++kt) {
        int cur = kt & 1;
        if (kt < 31) stage(cur ^ 1, kt + 1);
        bf16x8 af[4], bfv[4];
#pragma unroll
        for (int mi = 0; mi < 4; mi++)
            af[mi] = *(const bf16x8*)&Asm[cur][(wr * 64 + mi * 16 + lrow) * 32 + g * 8];
#pragma unroll
        for (int nj = 0; nj < 4; nj++)
            bfv[nj] = *(const bf16x8*)&Bsm[cur][(wc * 64 + nj * 16 + lrow) * 32 + g * 8];
#pragma unroll
        for (int mi = 0; mi < 4; mi++)
#pragma unroll
            for (int nj = 0; nj < 4; nj++)
                acc[mi][nj] = __builtin_amdgcn_mfma_f32_16x16x32_bf16(af[mi], bfv[nj], acc[mi][nj], 0, 0, 0);
        __syncthreads();
    }
#pragma unroll
    for (int nj = 0; nj < 4; nj++) {
        int n = bcol + wc * 64 + nj * 16 + lrow;
        float bv = bias[n];
#pragma unroll
        for (int mi = 0; mi < 4; mi++) {
#pragma unroll
            for (int r = 0; r < 4; r++) {
                int row = brow + wr * 64 + mi * 16 + g * 4 + r;
                float val = acc[mi][nj][r] + bv;
                if (OUT_BF16)
                    ((u16*)Cout)[(size_t)row * ldc + z * DMODEL + n] = (u16)bfr(val);
                else
                    ((float*)Cout)[(size_t)row * ldc + n] = val;
            }
        }
    }
}

// ---------- 4. flash attention (swapped QK^T, in-register softmax) ----------
// block = (qtile of 64 rows, b*h). 4 waves x 16 q-rows. KV blocks of 64.
// QK^T computed as mfma(K,Q) -> D[kv][q]: lane owns q=lane&15, kv=(lane>>4)*4+r.
__global__ __launch_bounds__(256) void attn(const u16* __restrict__ QKV, u16* __restrict__ CTX) {
    int bh = blockIdx.y;                // b*16 + h
    int qt = blockIdx.x;                // 0..31
    int h = bh & 15;
    size_t base = (size_t)(bh >> 4) * TSEQ * 3072;
    int t = threadIdx.x, lane = t & 63, wid = t >> 6;
    int lrow = lane & 15, g = lane >> 4;

    __shared__ __align__(16) u16 Kl[2][4096];   // [kv][64] d-chunk-swizzled
    __shared__ __align__(16) u16 Vl[2][4096];   // transposed [d][kv], XOR layout
    __shared__ __align__(16) u16 Pl[4][1024];   // per-wave P [16 q][64 kv], 16B-XOR swizzled

    // Q fragments (hoisted, registers). B-operand: lane holds col q=lane&15.
    int qrow = qt * 64 + wid * 16 + lrow;
    const u16* Qp = QKV + base + (size_t)qrow * 3072 + h * 64;
    bf16x8 aq0 = *(const bf16x8*)(Qp + g * 8);
    bf16x8 aq1 = *(const bf16x8*)(Qp + 32 + g * 8);

    f32x4 zero4 = {0.f, 0.f, 0.f, 0.f};
    f32x4 o[4];
#pragma unroll
    for (int nj = 0; nj < 4; nj++) o[nj] = zero4;
    float m_ = -1e30f, l_ = 0.f;                // per-lane: stats for q = lane&15
    const float C = 0.18033688f;                // 0.125 * log2(e)
    const float THR = 44.3614195f;              // 8 / C : defer-max threshold

    char* plbase = (char*)&Pl[wid][0] + lrow * 128;
    int xq = (lrow & 7) << 4;

    // V staging assignment: thread -> (kv pair, 8-wide d block)
    int vkv = (t & 31) * 2;
    int vd0 = (t >> 5) * 8;
    u16x8 vr0, vr1;

    auto stageK = [&](int buf, int kvb) {
#pragma unroll
        for (int i = 0; i < 2; i++) {
            int c = i * 256 + wid * 64 + lane;
            int kv = c >> 3, kc = (c & 7) ^ (kv & 7);     // pre-swizzled source
            gl_lds16(QKV + base + (size_t)(kvb * 64 + kv) * 3072 + 1024 + h * 64 + kc * 8,
                     &Kl[buf][(i * 256 + wid * 64) * 8]);
        }
    };
    auto loadV = [&](int kvb) {
        const u16* Vp = QKV + base + (size_t)(kvb * 64) * 3072 + 2048 + h * 64;
        vr0 = *(const u16x8*)(Vp + (size_t)vkv * 3072 + vd0);
        vr1 = *(const u16x8*)(Vp + (size_t)(vkv + 1) * 3072 + vd0);
    };
    auto writeV = [&](int buf) {
#pragma unroll
        for (int e = 0; e < 8; e++) {
            int d = vd0 + e;
            int kvs = vkv ^ ((d >> 4) << 4) ^ ((d & 7) << 3);
            u32 p = (u32)vr0[e] | ((u32)vr1[e] << 16);
            *(u32*)&Vl[buf][d * 64 + kvs] = p;
        }
    };

    stageK(0, 0);
    loadV(0);
    writeV(0);
    __syncthreads();

    for (int kvb = 0; kvb < 32; ++kvb) {
        int cur = kvb & 1, nxt = cur ^ 1;
        if (kvb < 31) { stageK(nxt, kvb + 1); loadV(kvb + 1); }

        // ---- QK^T swapped: s4[tt] = K-tile * Q^T -> D[kv][q] ----
        f32x4 s4[4];
#pragma unroll
        for (int tt = 0; tt < 4; tt++) {
            int kvl = tt * 16 + lrow;
            bf16x8 bk0 = *(const bf16x8*)&Kl[cur][kvl * 64 + ((g ^ (kvl & 7)) * 8)];
            bf16x8 bk1 = *(const bf16x8*)&Kl[cur][kvl * 64 + (((4 + g) ^ (kvl & 7)) * 8)];
            f32x4 acc = zero4;
            acc = __builtin_amdgcn_mfma_f32_16x16x32_bf16(bk0, aq0, acc, 0, 0, 0);
            acc = __builtin_amdgcn_mfma_f32_16x16x32_bf16(bk1, aq1, acc, 0, 0, 0);
            s4[tt] = acc;
        }

        // ---- online softmax: lane owns row q = lane&15, 16 kv values in regs ----
        float pa01 = fmaxf(fmaxf(s4[0][0], s4[0][1]), fmaxf(s4[0][2], s4[0][3]));
        float pa23 = fmaxf(fmaxf(s4[1][0], s4[1][1]), fmaxf(s4[1][2], s4[1][3]));
        float pb01 = fmaxf(fmaxf(s4[2][0], s4[2][1]), fmaxf(s4[2][2], s4[2][3]));
        float pb23 = fmaxf(fmaxf(s4[3][0], s4[3][1]), fmaxf(s4[3][2], s4[3][3]));
        float pm = fmaxf(fmaxf(pa01, pa23), fmaxf(pb01, pb23));
        pm = fmaxf(pm, __shfl_xor(pm, 16));
        pm = fmaxf(pm, __shfl_xor(pm, 32));

        if (!__all(pm <= m_ + THR)) {           // defer-max: rescale only on real growth
            float mn = fmaxf(m_, pm);
            float corr = __builtin_amdgcn_exp2f((m_ - mn) * C);
            m_ = mn;
            l_ *= corr;
#pragma unroll
            for (int r = 0; r < 4; r++) {
                float cr = __shfl(corr, g * 4 + r);
#pragma unroll
                for (int nj = 0; nj < 4; nj++) o[nj][r] *= cr;
            }
        }

        // ---- P = exp2(s*C - m*C), pack pairs, ds_write_b64 per tile ----
        float nmC = m_ * C;
        float ls = 0.f;
#pragma unroll
        for (int tt = 0; tt < 4; tt++) {
            float p0 = __builtin_amdgcn_exp2f(__builtin_fmaf(s4[tt][0], C, -nmC));
            float p1 = __builtin_amdgcn_exp2f(__builtin_fmaf(s4[tt][1], C, -nmC));
            float p2 = __builtin_amdgcn_exp2f(__builtin_fmaf(s4[tt][2], C, -nmC));
            float p3 = __builtin_amdgcn_exp2f(__builtin_fmaf(s4[tt][3], C, -nmC));
            ls += (p0 + p1) + (p2 + p3);
            uint2 w;
            w.x = cvtpk(p0, p1);
            w.y = cvtpk(p2, p3);
            *(uint2*)(plbase + ((tt * 32 + g * 8) ^ xq)) = w;
        }
        ls += __shfl_xor(ls, 16);
        ls += __shfl_xor(ls, 32);
        l_ += ls;

        if (kvb < 31) writeV(nxt);

        // ---- PV: o[q][d] += P @ V  (A = P rows q, B = V^T rows d) ----
#pragma unroll
        for (int kc = 0; kc < 2; kc++) {
            bf16x8 pa = *(const bf16x8*)(plbase + ((kc * 64 + g * 16) ^ xq));
#pragma unroll
            for (int nj = 0; nj < 4; nj++) {
                int d = nj * 16 + lrow;
                bf16x8 vb = *(const bf16x8*)&Vl[cur][d * 64 + ((kc * 32 + g * 8) ^ (nj << 4) ^ ((lrow & 7) << 3))];
                o[nj] = __builtin_amdgcn_mfma_f32_16x16x32_bf16(pa, vb, o[nj], 0, 0, 0);
            }
        }
        __syncthreads();
    }

    // ---- store ctx (bf16); o rows are q = g*4+r, broadcast l from lane q ----
    float rln[4];
#pragma unroll
    for (int r = 0; r < 4; r++) {
        float ln = __shfl(l_, g * 4 + r);
        rln[r] = 1.0f / ln;
    }
#pragma unroll
    for (int nj = 0; nj < 4; nj++) {
#pragma unroll
        for (int r = 0; r < 4; r++) {
            int row = qt * 64 + wid * 16 + g * 4 + r;
            float val = o[nj][r] * rln[r];
            CTX[((size_t)(bh >> 4) * TSEQ + row) * DMODEL + h * 64 + nj * 16 + lrow] = (u16)bfr(val);
        }
    }
}

// ---------- launch ----------
extern "C" void kernel_launch(void* const* d_in, const int* in_sizes, int n_in,
                              void* d_out, int out_size, void* d_ws, size_t ws_size,
                              hipStream_t stream) {
    const float* q  = (const float*)d_in[0];
    const float* k  = (const float*)d_in[1];
    const float* v  = (const float*)d_in[2];
    const float* Wq = (const float*)d_in[3];
    const float* bq = (const float*)d_in[4];
    const float* Wk = (const float*)d_in[5];
    const float* bk = (const float*)d_in[6];
    const float* Wv = (const float*)d_in[7];
    const float* bv = (const float*)d_in[8];
    const float* Wo = (const float*)d_in[9];
    const float* bo = (const float*)d_in[10];

    char* ws = (char*)d_ws;
    u16* Xbf = (u16*)ws;                               // 3 * 4096*1024 bf16 = 25165824 B
    u16* Wt  = (u16*)(ws + 25165824);                  // 4 * 1024*1024 bf16 =  8388608 B
    u16* QKV = (u16*)(ws + 25165824 + 8388608);        // 4096*3072 bf16    = 25165824 B
    u16* CTX = Xbf;                                    // reuse (Xbf dead after proj GEMM)

    cvt_x<<<dim3(2048, 3), 256, 0, stream>>>(q, k, v, Xbf);
    cvt_w<<<dim3(32, 32, 4), 256, 0, stream>>>(Wq, Wk, Wv, Wo, Wt);
    gemm_bt<1><<<dim3(8, 32, 3), 256, 0, stream>>>(Xbf, Wt, bq, bk, bv, QKV, 3072);
    attn<<<dim3(32, 32), 256, 0, stream>>>(QKV, CTX);
    gemm_bt<0><<<dim3(8, 32, 1), 256, 0, stream>>>(CTX, Wt + 3 * 1048576, bo, bo, bo, d_out, 1024);
}

// Round 6
// 151.265 us; speedup vs baseline: 1.5465x; 1.2607x over previous
//
#include <hip/hip_runtime.h>

typedef __bf16 bf16x8 __attribute__((ext_vector_type(8)));
typedef float f32x4 __attribute__((ext_vector_type(4)));
typedef float f32x16 __attribute__((ext_vector_type(16)));
typedef unsigned short u16;
typedef unsigned short u16x8 __attribute__((ext_vector_type(8)));
typedef unsigned int u32;

#define MROWS 4096      // B*T
#define DMODEL 1024
#define TSEQ 2048

// ---------- helpers ----------
__device__ __forceinline__ u32 bfr(float x) {          // fp32 -> bf16 bits, RNE
    u32 u = __float_as_uint(x);
    return (u + 0x7FFFu + ((u >> 16) & 1u)) >> 16;
}
__device__ __forceinline__ u32 pk2(float lo, float hi) { return bfr(lo) | (bfr(hi) << 16); }

__device__ __forceinline__ u32 cvtpk(float lo, float hi) {  // D.lo=bf16(lo), D.hi=bf16(hi)
    u32 r;
    asm("v_cvt_pk_bf16_f32 %0, %1, %2" : "=v"(r) : "v"(lo), "v"(hi));
    return r;
}

__device__ __forceinline__ void gl_lds16(const void* g, void* l) {
    __builtin_amdgcn_global_load_lds(
        (const __attribute__((address_space(1))) unsigned int*)g,
        (__attribute__((address_space(3))) unsigned int*)l, 16, 0, 0);
}

// ---------- 1. convert q,k,v to bf16 ----------
__global__ __launch_bounds__(256) void cvt_x(const float* __restrict__ q,
                                             const float* __restrict__ k,
                                             const float* __restrict__ v,
                                             u16* __restrict__ X) {
    int z = blockIdx.y;
    const float* src = (z == 0) ? q : (z == 1) ? k : v;
    size_t idx = ((size_t)blockIdx.x * 256 + threadIdx.x) * 8;
    const float4* s4 = (const float4*)(src + idx);
    float4 a = s4[0], b = s4[1];
    uint4 r;
    r.x = pk2(a.x, a.y); r.y = pk2(a.z, a.w);
    r.z = pk2(b.x, b.y); r.w = pk2(b.z, b.w);
    *(uint4*)(X + (size_t)z * 4194304 + idx) = r;
}

// ---------- 2. convert + transpose weights: Wt[n][k] = W[k][n], bf16 ----------
__global__ __launch_bounds__(256) void cvt_w(const float* __restrict__ w0,
                                             const float* __restrict__ w1,
                                             const float* __restrict__ w2,
                                             const float* __restrict__ w3,
                                             u16* __restrict__ Wt) {
    int z = blockIdx.z;
    const float* W = (z == 0) ? w0 : (z == 1) ? w1 : (z == 2) ? w2 : w3;
    u16* dst = Wt + (size_t)z * 1048576;
    __shared__ float tile[32][33];
    int n0 = blockIdx.x * 32, k0 = blockIdx.y * 32;
    int tx = threadIdx.x & 31, ty = threadIdx.x >> 5;
#pragma unroll
    for (int r = 0; r < 4; r++) {
        int row = ty + r * 8;
        tile[row][tx] = W[(size_t)(k0 + row) * DMODEL + n0 + tx];
    }
    __syncthreads();
#pragma unroll
    for (int r = 0; r < 4; r++) {
        int row = ty + r * 8;
        dst[(size_t)(n0 + row) * DMODEL + k0 + tx] = (u16)bfr(tile[tx][row]);
    }
}

// ---------- 3/5. GEMM: C[M,128-tile] = A[M,1024] @ Bt[n][k]^T + bias ----------
template <int OUT_BF16>
__global__ __launch_bounds__(256) void gemm_bt(const u16* __restrict__ Abase,
                                               const u16* __restrict__ Btbase,
                                               const float* __restrict__ b0,
                                               const float* __restrict__ b1,
                                               const float* __restrict__ b2,
                                               void* __restrict__ Cout, int ldc) {
    int z = blockIdx.z;
    const u16* A  = Abase + (size_t)z * MROWS * DMODEL;
    const u16* Bt = Btbase + (size_t)z * DMODEL * DMODEL;
    const float* bias = (z == 0) ? b0 : (z == 1) ? b1 : b2;
    int brow = blockIdx.y * 128, bcol = blockIdx.x * 128;
    int t = threadIdx.x, lane = t & 63, wid = t >> 6;
    int wr = wid >> 1, wc = wid & 1;
    int lrow = lane & 15, g = lane >> 4;

    __shared__ __align__(16) u16 Asm[2][128 * 32];
    __shared__ __align__(16) u16 Bsm[2][128 * 32];

    f32x4 zero4 = {0.f, 0.f, 0.f, 0.f};
    f32x4 acc[4][4];
#pragma unroll
    for (int i = 0; i < 4; i++)
#pragma unroll
        for (int j = 0; j < 4; j++) acc[i][j] = zero4;

    auto stage = [&](int buf, int kt) {
        int k0 = kt * 32;
#pragma unroll
        for (int i = 0; i < 2; i++) {
            int c = i * 256 + wid * 64 + lane;
            int row = c >> 2, kc = c & 3;
            gl_lds16(A + (size_t)(brow + row) * DMODEL + k0 + kc * 8,
                     &Asm[buf][(i * 256 + wid * 64) * 8]);
            gl_lds16(Bt + (size_t)(bcol + row) * DMODEL + k0 + kc * 8,
                     &Bsm[buf][(i * 256 + wid * 64) * 8]);
        }
    };

    stage(0, 0);
    __syncthreads();
    for (int kt = 0; kt < 32; ++kt) {
        int cur = kt & 1;
        if (kt < 31) stage(cur ^ 1, kt + 1);
        bf16x8 af[4], bfv[4];
#pragma unroll
        for (int mi = 0; mi < 4; mi++)
            af[mi] = *(const bf16x8*)&Asm[cur][(wr * 64 + mi * 16 + lrow) * 32 + g * 8];
#pragma unroll
        for (int nj = 0; nj < 4; nj++)
            bfv[nj] = *(const bf16x8*)&Bsm[cur][(wc * 64 + nj * 16 + lrow) * 32 + g * 8];
#pragma unroll
        for (int mi = 0; mi < 4; mi++)
#pragma unroll
            for (int nj = 0; nj < 4; nj++)
                acc[mi][nj] = __builtin_amdgcn_mfma_f32_16x16x32_bf16(af[mi], bfv[nj], acc[mi][nj], 0, 0, 0);
        __syncthreads();
    }
#pragma unroll
    for (int nj = 0; nj < 4; nj++) {
        int n = bcol + wc * 64 + nj * 16 + lrow;
        float bv = bias[n];
#pragma unroll
        for (int mi = 0; mi < 4; mi++) {
#pragma unroll
            for (int r = 0; r < 4; r++) {
                int row = brow + wr * 64 + mi * 16 + g * 4 + r;
                float val = acc[mi][nj][r] + bv;
                if (OUT_BF16)
                    ((u16*)Cout)[(size_t)row * ldc + z * DMODEL + n] = (u16)bfr(val);
                else
                    ((float*)Cout)[(size_t)row * ldc + n] = val;
            }
        }
    }
}

// ---------- 4. flash attention: 32x32 MFMA, QBLK=32/wave, in-register P ----------
// block = 4 waves x 32 q = 128 q-rows, grid (16, 32). KV blocks of 64.
// Swapped QK^T: D[kv][q], col q = lane&31 (lane-local q), row kv = (r&3)+8*(r>>2)+4*hf.
// PV uses a custom (A,B)-consistent kv slot map kappa(h,j) = 8*(j>>2)+4*h+(j&3):
// the lane's NATIVE p-register order IS the A-frag order (pa[kc] = pack(p[8kc..+7])),
// so P needs NO cross-lane movement; V's LDS layout swaps kv bits 2<->3 to match.
// Cross-half (q <-> q+32) reductions via __shfl_xor(,32) (validated in round 2).
__global__ __launch_bounds__(256) void attn(const u16* __restrict__ QKV, u16* __restrict__ CTX) {
    int bh = blockIdx.y;                // b*16 + head
    int qt = blockIdx.x;                // 0..15
    int head = bh & 15;
    size_t base = (size_t)(bh >> 4) * TSEQ * 3072;
    int t = threadIdx.x, lane = t & 63, wid = t >> 6;
    int l31 = lane & 31, hf = lane >> 5;

    __shared__ __align__(16) u16 Kl[2][4096];   // [kv][8 slots of 8 bf16], slot ^= (kv&7)
    __shared__ __align__(16) u16 Vl[2][4096];   // transposed [d][kv], bit2<->3 + XOR layout

    // Q fragments (B-operand): lane holds Q[q = qbase+l31][d = c*16 + hf*8 + j]
    int qbase = qt * 128 + wid * 32;
    const u16* Qp = QKV + base + (size_t)(qbase + l31) * 3072 + head * 64;
    bf16x8 qf[4];
#pragma unroll
    for (int c = 0; c < 4; c++) qf[c] = *(const bf16x8*)(Qp + c * 16 + hf * 8);

    f32x16 o0 = {}, o1 = {};
    float m_ = -1e30f, l_ = 0.f;                // per-lane stats for q = l31
    const float C = 0.18033688f;                // 0.125 * log2(e)
    const float THR = 44.3614195f;              // 8 / C : defer-max threshold

    // V staging assignment: thread -> (kv pair, 8-wide d block)
    int vkv = (t & 31) * 2;
    int vd0 = (t >> 5) * 8;
    int vslot = (vkv & ~12) | ((vkv & 4) << 1) | ((vkv & 8) >> 1);  // kv bits 2<->3
    u16x8 vr0, vr1;

    auto stageK = [&](int buf, int kvb) {
#pragma unroll
        for (int i = 0; i < 2; i++) {
            int c = i * 256 + wid * 64 + lane;
            int kv = c >> 3, kc = (c & 7) ^ (kv & 7);     // pre-swizzled source
            gl_lds16(QKV + base + (size_t)(kvb * 64 + kv) * 3072 + 1024 + head * 64 + kc * 8,
                     &Kl[buf][(i * 256 + wid * 64) * 8]);
        }
    };
    auto loadV = [&](int kvb) {
        const u16* Vp = QKV + base + (size_t)(kvb * 64) * 3072 + 2048 + head * 64;
        vr0 = *(const u16x8*)(Vp + (size_t)vkv * 3072 + vd0);
        vr1 = *(const u16x8*)(Vp + (size_t)(vkv + 1) * 3072 + vd0);
    };
    auto writeV = [&](int buf) {
#pragma unroll
        for (int e = 0; e < 8; e++) {
            int d = vd0 + e;
            int kvs = vslot ^ ((d >> 4) << 4) ^ ((d & 7) << 3);
            u32 p = (u32)vr0[e] | ((u32)vr1[e] << 16);
            *(u32*)&Vl[buf][d * 64 + kvs] = p;
        }
    };

    stageK(0, 0);
    loadV(0);
    writeV(0);
    __syncthreads();

    int kx = (l31 & 7) * 8;                     // K read swizzle (bf16 units)
    const float mC = C;

    for (int kvb = 0; kvb < 32; ++kvb) {
        int cur = kvb & 1, nxt = cur ^ 1;
        if (kvb < 31) { stageK(nxt, kvb + 1); loadV(kvb + 1); }

        // ---- QK^T swapped: s0 = K[0..31] x Q^T, s1 = K[32..63] x Q^T ----
        f32x16 s0 = {}, s1 = {};
        const u16* kr0 = &Kl[cur][(size_t)l31 * 64];
        const u16* kr1 = kr0 + 32 * 64;
        __builtin_amdgcn_s_setprio(1);
#pragma unroll
        for (int c = 0; c < 4; c++) {
            int slot = ((2 * c + hf) * 8) ^ kx;
            bf16x8 a0 = *(const bf16x8*)(kr0 + slot);
            bf16x8 a1 = *(const bf16x8*)(kr1 + slot);
            s0 = __builtin_amdgcn_mfma_f32_32x32x16_bf16(a0, qf[c], s0, 0, 0, 0);
            s1 = __builtin_amdgcn_mfma_f32_32x32x16_bf16(a1, qf[c], s1, 0, 0, 0);
        }
        __builtin_amdgcn_s_setprio(0);

        // ---- online softmax: lane owns q = l31; 32 kv values in regs ----
        float x0 = fmaxf(fmaxf(s0[0], s0[1]), fmaxf(s0[2], s0[3]));
        float x1 = fmaxf(fmaxf(s0[4], s0[5]), fmaxf(s0[6], s0[7]));
        float x2 = fmaxf(fmaxf(s0[8], s0[9]), fmaxf(s0[10], s0[11]));
        float x3 = fmaxf(fmaxf(s0[12], s0[13]), fmaxf(s0[14], s0[15]));
        float y0 = fmaxf(fmaxf(s1[0], s1[1]), fmaxf(s1[2], s1[3]));
        float y1 = fmaxf(fmaxf(s1[4], s1[5]), fmaxf(s1[6], s1[7]));
        float y2 = fmaxf(fmaxf(s1[8], s1[9]), fmaxf(s1[10], s1[11]));
        float y3 = fmaxf(fmaxf(s1[12], s1[13]), fmaxf(s1[14], s1[15]));
        float pm = fmaxf(fmaxf(fmaxf(x0, x1), fmaxf(x2, x3)),
                         fmaxf(fmaxf(y0, y1), fmaxf(y2, y3)));
        pm = fmaxf(pm, __shfl_xor(pm, 32));     // combine q-row halves (lane ^ 32)

        if (!__all(pm <= m_ + THR)) {           // defer-max: rescale only on real growth
            float mn = fmaxf(m_, pm);
            float corr = __builtin_amdgcn_exp2f((m_ - mn) * mC);
            m_ = mn;
            l_ *= corr;
#pragma unroll
            for (int r = 0; r < 16; r++) {
                int qr = (r & 3) + 8 * (r >> 2) + 4 * hf;
                float cr = __shfl(corr, qr);
                o0[r] *= cr; o1[r] *= cr;
            }
        }

        // ---- P = exp2(s*C - m*C) ----
        float nm = m_ * mC;
        float p0[16], p1[16];
#pragma unroll
        for (int r = 0; r < 16; r++) {
            p0[r] = __builtin_amdgcn_exp2f(__builtin_fmaf(s0[r], mC, -nm));
            p1[r] = __builtin_amdgcn_exp2f(__builtin_fmaf(s1[r], mC, -nm));
        }
        float la = 0.f, lb = 0.f, lc = 0.f, ld = 0.f;
#pragma unroll
        for (int r = 0; r < 4; r++) {
            la += p0[r] + p0[r + 4];
            lb += p0[r + 8] + p0[r + 12];
            lc += p1[r] + p1[r + 4];
            ld += p1[r + 8] + p1[r + 12];
        }
        float ls = (la + lb) + (lc + ld);
        ls += __shfl_xor(ls, 32);               // combine q-row halves (lane ^ 32)
        l_ += ls;

        // ---- pack P -> PV A-frags DIRECTLY (native register order = frag order) ----
        union FragU { u32 u[4]; bf16x8 v; };
        FragU fA, fB, fC, fD;
#pragma unroll
        for (int w = 0; w < 4; w++) {
            fA.u[w] = cvtpk(p0[2 * w],     p0[2 * w + 1]);
            fB.u[w] = cvtpk(p0[8 + 2 * w], p0[9 + 2 * w]);
            fC.u[w] = cvtpk(p1[2 * w],     p1[2 * w + 1]);
            fD.u[w] = cvtpk(p1[8 + 2 * w], p1[9 + 2 * w]);
        }
        bf16x8 pa[4] = {fA.v, fB.v, fC.v, fD.v};

        if (kvb < 31) writeV(nxt);

        // ---- PV: o[q][d] += P @ V ----
        __builtin_amdgcn_s_setprio(1);
#pragma unroll
        for (int kc = 0; kc < 4; kc++) {
            int d0 = l31;
            int sl0 = ((2 * kc + hf) ^ (d0 & 7) ^ ((d0 >> 4) << 1)) * 8;
            bf16x8 v0 = *(const bf16x8*)&Vl[cur][d0 * 64 + sl0];
            int d1 = 32 + l31;
            int sl1 = ((2 * kc + hf) ^ (d1 & 7) ^ ((d1 >> 4) << 1)) * 8;
            bf16x8 v1 = *(const bf16x8*)&Vl[cur][d1 * 64 + sl1];
            o0 = __builtin_amdgcn_mfma_f32_32x32x16_bf16(pa[kc], v0, o0, 0, 0, 0);
            o1 = __builtin_amdgcn_mfma_f32_32x32x16_bf16(pa[kc], v1, o1, 0, 0, 0);
        }
        __builtin_amdgcn_s_setprio(0);
        __syncthreads();
    }

    // ---- store ctx (bf16); o rows are q = (r&3)+8*(r>>2)+4*hf ----
#pragma unroll
    for (int r = 0; r < 16; r++) {
        int qr = (r & 3) + 8 * (r >> 2) + 4 * hf;
        float rl = 1.0f / __shfl(l_, qr);
        size_t rowoff = ((size_t)(bh >> 4) * TSEQ + qbase + qr) * DMODEL + head * 64;
        CTX[rowoff + l31]      = (u16)bfr(o0[r] * rl);
        CTX[rowoff + 32 + l31] = (u16)bfr(o1[r] * rl);
    }
}

// ---------- launch ----------
extern "C" void kernel_launch(void* const* d_in, const int* in_sizes, int n_in,
                              void* d_out, int out_size, void* d_ws, size_t ws_size,
                              hipStream_t stream) {
    const float* q  = (const float*)d_in[0];
    const float* k  = (const float*)d_in[1];
    const float* v  = (const float*)d_in[2];
    const float* Wq = (const float*)d_in[3];
    const float* bq = (const float*)d_in[4];
    const float* Wk = (const float*)d_in[5];
    const float* bk = (const float*)d_in[6];
    const float* Wv = (const float*)d_in[7];
    const float* bv = (const float*)d_in[8];
    const float* Wo = (const float*)d_in[9];
    const float* bo = (const float*)d_in[10];

    char* ws = (char*)d_ws;
    u16* Xbf = (u16*)ws;                               // 3 * 4096*1024 bf16 = 25165824 B
    u16* Wt  = (u16*)(ws + 25165824);                  // 4 * 1024*1024 bf16 =  8388608 B
    u16* QKV = (u16*)(ws + 25165824 + 8388608);        // 4096*3072 bf16    = 25165824 B
    u16* CTX = Xbf;                                    // reuse (Xbf dead after proj GEMM)

    cvt_x<<<dim3(2048, 3), 256, 0, stream>>>(q, k, v, Xbf);
    cvt_w<<<dim3(32, 32, 4), 256, 0, stream>>>(Wq, Wk, Wv, Wo, Wt);
    gemm_bt<1><<<dim3(8, 32, 3), 256, 0, stream>>>(Xbf, Wt, bq, bk, bv, QKV, 3072);
    attn<<<dim3(16, 32), 256, 0, stream>>>(QKV, CTX);
    gemm_bt<0><<<dim3(8, 32, 1), 256, 0, stream>>>(CTX, Wt + 3 * 1048576, bo, bo, bo, d_out, 1024);
}